// Round 1
// baseline (424.748 us; speedup 1.0000x reference)
//
#include <hip/hip_runtime.h>
#include <math.h>

// Problem constants (B=4, C=128, H=W=64, k=3, O=128, stride=1, pad=1)
#define NB 4
#define NC 128
#define NH 64
#define NW 64
#define NO 128
#define NT 9

// Workspace layout (float offsets)
#define XT_OFF   0                         // [4][64][64][128] NHWC x      : 2097152
#define OFF_OFF  2097152                   // [4][27][64][64] off(18)+mask(9): 442368
#define WT_OFF   (OFF_OFF + 442368)        // [9][128][128] WT[t][c][o]    : 147456
#define WR_OFF   (WT_OFF + 147456)         // [27][9][128]  WR[oc][t][c]   : 31104
#define BNS_OFF  (WR_OFF + 31104)          // [128] scale
#define BNB_OFF  (BNS_OFF + 128)           // [128] shift
#define WS_FLOATS (BNB_OFF + 128)

// ---------------------------------------------------------------------------
// prep: NCHW->NHWC transpose, weight rearrangements, BN fold
// ---------------------------------------------------------------------------
__global__ __launch_bounds__(256) void prep_kernel(
    const float* __restrict__ x,   const float* __restrict__ ow,
    const float* __restrict__ mw,  const float* __restrict__ wgt,
    const float* __restrict__ gam, const float* __restrict__ bet,
    const float* __restrict__ mean,const float* __restrict__ var,
    float* __restrict__ ws) {
  const int N_XT = 2097152, N_WT = 147456, N_WR = 31104;
  int i = blockIdx.x * 256 + threadIdx.x;
  if (i < N_XT) {
    int c = i & 127, xx = (i >> 7) & 63, y = (i >> 13) & 63, b = i >> 19;
    ws[XT_OFF + i] = x[((b * 128 + c) * 64 + y) * 64 + xx];
  } else if (i < N_XT + N_WT) {
    int j = i - N_XT;
    int o = j & 127, c = (j >> 7) & 127, t = j >> 14;
    ws[WT_OFF + j] = wgt[(o * 128 + c) * 9 + t];
  } else if (i < N_XT + N_WT + N_WR) {
    int j = i - N_XT - N_WT;
    int c = j & 127, t = (j >> 7) % 9, oc = j / 1152;
    ws[WR_OFF + j] = (oc < 18) ? ow[(oc * 128 + c) * 9 + t]
                               : mw[((oc - 18) * 128 + c) * 9 + t];
  } else if (i < N_XT + N_WT + N_WR + 128) {
    int o = i - (N_XT + N_WT + N_WR);
    float s = gam[o] * rsqrtf(var[o] + 1e-5f);
    ws[BNS_OFF + o] = s;
    ws[BNB_OFF + o] = bet[o] - mean[o] * s;
  }
}

// ---------------------------------------------------------------------------
// offset+mask 3x3 conv (128 -> 27 channels), mask pre-sigmoided.
// Block = one (b, ho) row. lanes: oc = tid&31 (27 live), pg = tid>>5 -> 8 pos.
// ---------------------------------------------------------------------------
__global__ __launch_bounds__(256) void offmask_kernel(
    float* __restrict__ ws, const float* __restrict__ ob,
    const float* __restrict__ mb) {
  int b = blockIdx.x >> 6, ho = blockIdx.x & 63;
  int tid = threadIdx.x;
  int oc = tid & 31, pg = tid >> 5, p0 = pg * 8;
  int oce = oc < 27 ? oc : 26;
  const float* XT = ws + XT_OFF;
  const float* WR = ws + WR_OFF;

  float bias = (oce < 18) ? ob[oce] : mb[oce - 18];
  float acc[8];
#pragma unroll
  for (int j = 0; j < 8; ++j) acc[j] = bias;

  for (int dy = 0; dy < 3; ++dy) {
    int y = ho - 1 + dy;
    if ((unsigned)y >= 64u) continue;
    const float* xrow = XT + ((b * 64 + y) * 64) * 128;
    for (int c4 = 0; c4 < 32; ++c4) {
      int c = c4 * 4;
      float4 xv[10];
#pragma unroll
      for (int j = 0; j < 10; ++j) {
        int xx = p0 - 1 + j;
        xv[j] = ((unsigned)xx < 64u) ? *(const float4*)(xrow + xx * 128 + c)
                                     : make_float4(0.f, 0.f, 0.f, 0.f);
      }
#pragma unroll
      for (int dx = 0; dx < 3; ++dx) {
        int t = dy * 3 + dx;
        float4 wv = *(const float4*)(WR + (oce * 9 + t) * 128 + c);
#pragma unroll
        for (int pi = 0; pi < 8; ++pi) {
          float4 xq = xv[pi + dx];
          acc[pi] += wv.x * xq.x + wv.y * xq.y + wv.z * xq.z + wv.w * xq.w;
        }
      }
    }
  }
  if (oc < 27) {
    float* dst = ws + OFF_OFF + ((b * 27 + oc) * 64 + ho) * 64 + p0;
#pragma unroll
    for (int pi = 0; pi < 8; ++pi) {
      float v = acc[pi];
      if (oc >= 18) v = 1.f / (1.f + __expf(-v));  // sigmoid for mask ch
      dst[pi] = v;
    }
  }
}

// ---------------------------------------------------------------------------
// main: deformable conv (implicit GEMM M=128,K=1152,N=64/block) + BN + SiLU
// Block = one (b, ho) row. Per tap: sample 64x128 modulated values into LDS,
// then register-tiled fp32 GEMM (8 o x 4 p per thread).
// ---------------------------------------------------------------------------
__global__ __launch_bounds__(256) void main_kernel(
    const float* __restrict__ ws, float* __restrict__ out) {
  __shared__ float Vt[64][132];  // pad 132: (4p+c)%32 banks -> <=2-way reads
  __shared__ float sly[64], slx[64], sm[64];
  __shared__ int sy0[64], sx0[64];

  int b = blockIdx.x >> 6, ho = blockIdx.x & 63;
  int tid = threadIdx.x;
  int og = tid >> 4, pg = tid & 15;   // o0 = og*8, p = pg + 16*j
  int o0 = og * 8;
  int cc = tid & 31, pr = tid >> 5;   // sampling map: c = 4*cc, p = pr*8+pass

  const float* XT = ws + XT_OFF;
  const float* OFF = ws + OFF_OFF;
  const float* WT = ws + WT_OFF;

  float acc[8][4];
#pragma unroll
  for (int r = 0; r < 8; ++r)
#pragma unroll
    for (int j = 0; j < 4; ++j) acc[r][j] = 0.f;

  for (int t = 0; t < 9; ++t) {
    __syncthreads();  // previous tap's GEMM must be done before overwrite
    if (tid < 64) {
      int p = tid;
      const float* offb = OFF + b * 27 * 4096 + ho * 64 + p;
      float oy = offb[(2 * t) * 4096];
      float ox = offb[(2 * t + 1) * 4096];
      float m = offb[(18 + t) * 4096];
      float py = (float)(ho - 1 + t / 3) + oy;
      float px = (float)(p - 1 + t % 3) + ox;
      float y0f = floorf(py), x0f = floorf(px);
      sy0[p] = (int)y0f;  sx0[p] = (int)x0f;
      sly[p] = py - y0f;  slx[p] = px - x0f;
      sm[p] = m;
    }
    __syncthreads();

    // ---- sampling phase: build Vt[p][c] = mask * bilinear(x) ----
    {
      int c = cc * 4;
      const float* base = XT + (b * 64) * 64 * 128 + c;
#pragma unroll
      for (int pass = 0; pass < 8; ++pass) {
        int p = pr * 8 + pass;
        int y0 = sy0[p], x0 = sx0[p];
        float ly = sly[p], lx = slx[p], m = sm[p];
        bool yv0 = (unsigned)y0 < 64u, yv1 = (unsigned)(y0 + 1) < 64u;
        bool xv0 = (unsigned)x0 < 64u, xv1 = (unsigned)(x0 + 1) < 64u;
        float4 z = make_float4(0.f, 0.f, 0.f, 0.f);
        float4 v00 = (yv0 && xv0) ? *(const float4*)(base + (y0 * 64 + x0) * 128) : z;
        float4 v01 = (yv0 && xv1) ? *(const float4*)(base + (y0 * 64 + x0 + 1) * 128) : z;
        float4 v10 = (yv1 && xv0) ? *(const float4*)(base + ((y0 + 1) * 64 + x0) * 128) : z;
        float4 v11 = (yv1 && xv1) ? *(const float4*)(base + ((y0 + 1) * 64 + x0 + 1) * 128) : z;
        float w00 = (1.f - ly) * (1.f - lx) * m;
        float w01 = (1.f - ly) * lx * m;
        float w10 = ly * (1.f - lx) * m;
        float w11 = ly * lx * m;
        float4 r;
        r.x = w00 * v00.x + w01 * v01.x + w10 * v10.x + w11 * v11.x;
        r.y = w00 * v00.y + w01 * v01.y + w10 * v10.y + w11 * v11.y;
        r.z = w00 * v00.z + w01 * v01.z + w10 * v10.z + w11 * v11.z;
        r.w = w00 * v00.w + w01 * v01.w + w10 * v10.w + w11 * v11.w;
        *(float4*)&Vt[p][c] = r;
      }
    }
    __syncthreads();

    // ---- GEMM phase: acc[o][p] += WT[t][c][o] * Vt[p][c] ----
    const float* Wt = WT + t * 128 * 128;
    for (int c4 = 0; c4 < 32; ++c4) {
      int c = c4 * 4;
      float4 w0[4], w1[4], vv[4];
#pragma unroll
      for (int q = 0; q < 4; ++q) {
        const float* wp = Wt + (c + q) * 128 + o0;
        w0[q] = *(const float4*)wp;
        w1[q] = *(const float4*)(wp + 4);
      }
#pragma unroll
      for (int j = 0; j < 4; ++j)
        vv[j] = *(const float4*)&Vt[pg + 16 * j][c];
#pragma unroll
      for (int j = 0; j < 4; ++j) {
        const float* vp = (const float*)&vv[j];
#pragma unroll
        for (int q = 0; q < 4; ++q) {
          float xs = vp[q];
          acc[0][j] += w0[q].x * xs;
          acc[1][j] += w0[q].y * xs;
          acc[2][j] += w0[q].z * xs;
          acc[3][j] += w0[q].w * xs;
          acc[4][j] += w1[q].x * xs;
          acc[5][j] += w1[q].y * xs;
          acc[6][j] += w1[q].z * xs;
          acc[7][j] += w1[q].w * xs;
        }
      }
    }
  }

  // ---- epilogue: BN + SiLU, coalesced stores ----
  const float* BNS = ws + BNS_OFF;
  const float* BNB = ws + BNB_OFF;
#pragma unroll
  for (int r = 0; r < 8; ++r) {
    int o = o0 + r;
    float s = BNS[o], sh = BNB[o];
    float* op = out + ((b * 128 + o) * 64 + ho) * 64;
#pragma unroll
    for (int j = 0; j < 4; ++j) {
      float v = acc[r][j] * s + sh;
      v = v / (1.f + __expf(-v));  // v * sigmoid(v)
      op[pg + 16 * j] = v;
    }
  }
}

extern "C" void kernel_launch(void* const* d_in, const int* in_sizes, int n_in,
                              void* d_out, int out_size, void* d_ws, size_t ws_size,
                              hipStream_t stream) {
  const float* x    = (const float*)d_in[0];
  const float* ow   = (const float*)d_in[1];
  const float* ob   = (const float*)d_in[2];
  const float* mw   = (const float*)d_in[3];
  const float* mb   = (const float*)d_in[4];
  const float* wgt  = (const float*)d_in[5];
  const float* gam  = (const float*)d_in[6];
  const float* bet  = (const float*)d_in[7];
  const float* mean = (const float*)d_in[8];
  const float* var  = (const float*)d_in[9];
  float* ws = (float*)d_ws;
  float* out = (float*)d_out;

  const int total = WS_FLOATS;  // grid covers all prep segments
  prep_kernel<<<(total + 255) / 256, 256, 0, stream>>>(x, ow, mw, wgt, gam, bet,
                                                       mean, var, ws);
  offmask_kernel<<<NB * NH, 256, 0, stream>>>(ws, ob, mb);
  main_kernel<<<NB * NH, 256, 0, stream>>>(ws, out);
}

// Round 2
// 147.672 us; speedup vs baseline: 2.8763x; 2.8763x over previous
//
#include <hip/hip_runtime.h>
#include <math.h>

typedef unsigned short u16;
typedef short bf16x8 __attribute__((ext_vector_type(8)));
typedef float f32x4 __attribute__((ext_vector_type(4)));

// Workspace byte offsets
#define XT_B    0u          // bf16 [4][64][64][128]  NHWC x
#define WF_B    4194304u    // bf16 [9][8][4][64][8]  main A-frags (t,mt,ks,lane,j)
#define WRF_B   4489216u    // bf16 [36][2][64][8]    offmask A-frags (ks,mt,lane,j)
#define OFFR_B  4562944u    // f32  [4][64][64][32]   offsets(18)+sigmask(9), pad 32
#define BNS_B   6660096u    // f32 [128] folded BN scale
#define BNB_B   6660608u    // f32 [128] folded BN shift

__device__ __forceinline__ float bf2f(u16 u) {
  union { unsigned int i; float f; } v; v.i = ((unsigned int)u) << 16; return v.f;
}
__device__ __forceinline__ u16 f2bf(float f) {
  union { float f; unsigned int i; } v; v.f = f;
  unsigned int i = v.i;
  return (u16)((i + 0x7fffu + ((i >> 16) & 1u)) >> 16);  // RNE
}

// ---------------------------------------------------------------------------
// prep: x -> bf16 NHWC (LDS-tiled transpose), weights -> MFMA A-frag order,
// BN fold. Grid = 977 blocks.
// ---------------------------------------------------------------------------
__global__ __launch_bounds__(256) void prep_kernel(
    const float* __restrict__ x,   const float* __restrict__ ow,
    const float* __restrict__ mw,  const float* __restrict__ wgt,
    const float* __restrict__ gam, const float* __restrict__ bet,
    const float* __restrict__ mean,const float* __restrict__ var,
    char* __restrict__ wsb) {
  int blk = blockIdx.x, tid = threadIdx.x;
  if (blk < 256) {  // transpose one (b,y) plane: [128c][64x] -> [64x][128c]
    __shared__ u16 tile[64][134];  // pad 134: write bank stride 3 words -> 2-way
    int b = blk >> 6, y = blk & 63;
    const float* src = x + (b * 128 * 64 + y) * 64;  // + c*4096 + xx
#pragma unroll
    for (int rep = 0; rep < 32; ++rep) {
      int flat = rep * 256 + tid;
      int c = flat >> 6, xx = flat & 63;          // lanes vary xx -> coalesced
      tile[xx][c] = f2bf(src[c * 4096 + xx]);
    }
    __syncthreads();
    u16* dst = (u16*)(wsb + XT_B) + ((b * 64 + y) * 64) * 128;
#pragma unroll
    for (int rep = 0; rep < 16; ++rep) {
      int flat = rep * 256 + tid;
      int xx = flat >> 6, c2 = (flat & 63) * 2;   // lanes vary c -> coalesced
      *(ushort2*)(dst + xx * 128 + c2) = make_ushort2(tile[xx][c2], tile[xx][c2 + 1]);
    }
  } else if (blk < 832) {  // main-weight A fragments
    int idx = (blk - 256) * 256 + tid;  // < 147456
    int jj = idx & 7, l = (idx >> 3) & 63, ks = (idx >> 9) & 3,
        mt = (idx >> 11) & 7, t = idx >> 14;
    int o = mt * 16 + (l & 15);
    int c = ks * 32 + (l >> 4) * 8 + jj;
    ((u16*)(wsb + WF_B))[idx] = f2bf(wgt[(o * 128 + c) * 9 + t]);
  } else if (blk < 976) {  // offmask-weight A fragments (27 rows, zero-pad to 32)
    int idx = (blk - 832) * 256 + tid;  // < 36864
    int jj = idx & 7, l = (idx >> 3) & 63, mt = (idx >> 9) & 1, ks = idx >> 10;
    int oc = mt * 16 + (l & 15);
    int k = ks * 32 + (l >> 4) * 8 + jj;
    int t = k >> 7, c = k & 127;
    float v = 0.f;
    if (oc < 18) v = ow[(oc * 128 + c) * 9 + t];
    else if (oc < 27) v = mw[((oc - 18) * 128 + c) * 9 + t];
    ((u16*)(wsb + WRF_B))[idx] = f2bf(v);
  } else {
    if (tid < 128) {
      float s = gam[tid] * rsqrtf(var[tid] + 1e-5f);
      ((float*)(wsb + BNS_B))[tid] = s;
      ((float*)(wsb + BNB_B))[tid] = bet[tid] - mean[tid] * s;
    }
  }
}

// ---------------------------------------------------------------------------
// offmask: 3x3 conv 128->27 via MFMA (M padded 32, K=1152, im2col B direct
// from bf16 NHWC x). Block = (b,ho,half): 32 p x 32 oc; wave = one 16x16 tile.
// Grid 512 x 256 threads.
// ---------------------------------------------------------------------------
__global__ __launch_bounds__(256) void offmask_kernel(
    char* __restrict__ wsb, const float* __restrict__ ob,
    const float* __restrict__ mb) {
  int blk = blockIdx.x;
  int b = blk >> 7, ho = (blk >> 1) & 63, half = blk & 1;
  int tid = threadIdx.x, w = tid >> 6, l = tid & 63;
  int mt = w >> 1, nt = w & 1, quad = l >> 4;
  int p = half * 32 + nt * 16 + (l & 15);
  const u16* XT = (const u16*)(wsb + XT_B);
  const u16* WRF = (const u16*)(wsb + WRF_B);
  f32x4 acc = {0.f, 0.f, 0.f, 0.f};
  bf16x8 bz = {0, 0, 0, 0, 0, 0, 0, 0};
#pragma unroll
  for (int t = 0; t < 9; ++t) {
    int y = ho + t / 3 - 1;
    int xx = p + t % 3 - 1;
    bool valid = ((unsigned)y < 64u) && ((unsigned)xx < 64u);
    const u16* bp = XT + ((b * 64 + y) * 64 + xx) * 128 + quad * 8;
#pragma unroll
    for (int kq = 0; kq < 4; ++kq) {
      int ks = t * 4 + kq;
      bf16x8 a = *(const bf16x8*)(WRF + ((ks * 2 + mt) * 64 + l) * 8);
      bf16x8 bb = valid ? *(const bf16x8*)(bp + kq * 32) : bz;
      acc = __builtin_amdgcn_mfma_f32_16x16x32_bf16(a, bb, acc, 0, 0, 0);
    }
  }
  float* OFFR = (float*)(wsb + OFFR_B);
#pragma unroll
  for (int r = 0; r < 4; ++r) {
    int oc = mt * 16 + quad * 4 + r;  // D: col=lane&15, row=quad*4+reg
    if (oc < 27) {
      float v = acc[r] + (oc < 18 ? ob[oc] : mb[oc - 18]);
      if (oc >= 18) v = 1.f / (1.f + __expf(-v));  // pre-sigmoid masks
      OFFR[((b * 64 + ho) * 64 + p) * 32 + oc] = v;
    }
  }
}

// ---------------------------------------------------------------------------
// main: deformable conv via MFMA + BN + SiLU.
// Block = (b,ho,quarter): 16 p x 128 O. Sample tap into LDS (bf16), MFMA
// consumes, double-buffered across taps. Grid 1024 x 256 threads.
// ---------------------------------------------------------------------------
__global__ __launch_bounds__(256) void main_kernel(
    const char* __restrict__ wsb, float* __restrict__ out) {
  __shared__ u16 vbuf[2][16][136];  // pitch 136: rows 16B-aligned, 2-way banks
  __shared__ float ply[9][16], plx[9][16], pmk[9][16];
  __shared__ int py0[9][16], px0[9][16];

  int blk = blockIdx.x;
  int b = blk >> 8, ho = (blk >> 2) & 63, qd = blk & 3;
  int p0 = qd * 16;
  int tid = threadIdx.x;
  const u16* XT = (const u16*)(wsb + XT_B);
  const u16* WF = (const u16*)(wsb + WF_B);
  const float* OFFR = (const float*)(wsb + OFFR_B);

  // bilinear params for all 9 taps x 16 positions
  if (tid < 144) {
    int t = tid >> 4, p = tid & 15;
    const float* op_ = OFFR + ((b * 64 + ho) * 64 + (p0 + p)) * 32;
    float oy = op_[2 * t], ox = op_[2 * t + 1], m = op_[18 + t];
    float py = (float)(ho + t / 3 - 1) + oy;
    float px = (float)(p0 + p + t % 3 - 1) + ox;
    float y0f = floorf(py), x0f = floorf(px);
    py0[t][p] = (int)y0f; px0[t][p] = (int)x0f;
    ply[t][p] = py - y0f;  plx[t][p] = px - x0f;
    pmk[t][p] = m;
  }
  __syncthreads();

  int c4 = tid & 31, pp = tid >> 5;
  int cch = c4 * 4;
  const u16* xbase = XT + b * 64 * 64 * 128 + cch;

  auto sample = [&](int t, int bi) {
#pragma unroll
    for (int i = 0; i < 2; ++i) {
      int p = pp * 2 + i;
      int y0 = py0[t][p], x0 = px0[t][p];
      float ly = ply[t][p], lx = plx[t][p], m = pmk[t][p];
      bool yv0 = (unsigned)y0 < 64u, yv1 = (unsigned)(y0 + 1) < 64u;
      bool xv0 = (unsigned)x0 < 64u, xv1 = (unsigned)(x0 + 1) < 64u;
      const u16* r0 = xbase + (y0 * 64 + x0) * 128;
      ushort4 z = make_ushort4(0, 0, 0, 0);
      ushort4 q00 = (yv0 && xv0) ? *(const ushort4*)(r0) : z;
      ushort4 q01 = (yv0 && xv1) ? *(const ushort4*)(r0 + 128) : z;
      ushort4 q10 = (yv1 && xv0) ? *(const ushort4*)(r0 + 8192) : z;
      ushort4 q11 = (yv1 && xv1) ? *(const ushort4*)(r0 + 8320) : z;
      float w00 = (1.f - ly) * (1.f - lx) * m, w01 = (1.f - ly) * lx * m;
      float w10 = ly * (1.f - lx) * m,        w11 = ly * lx * m;
      ushort4 o;
      o.x = f2bf(w00 * bf2f(q00.x) + w01 * bf2f(q01.x) + w10 * bf2f(q10.x) + w11 * bf2f(q11.x));
      o.y = f2bf(w00 * bf2f(q00.y) + w01 * bf2f(q01.y) + w10 * bf2f(q10.y) + w11 * bf2f(q11.y));
      o.z = f2bf(w00 * bf2f(q00.z) + w01 * bf2f(q01.z) + w10 * bf2f(q10.z) + w11 * bf2f(q11.z));
      o.w = f2bf(w00 * bf2f(q00.w) + w01 * bf2f(q01.w) + w10 * bf2f(q10.w) + w11 * bf2f(q11.w));
      *(ushort4*)&vbuf[bi][p][cch] = o;
    }
  };

  int w = tid >> 6, l = tid & 63, quad = l >> 4;
  f32x4 acc0 = {0.f, 0.f, 0.f, 0.f}, acc1 = {0.f, 0.f, 0.f, 0.f};

  auto dotap = [&](int t, int bi) {
#pragma unroll
    for (int ks = 0; ks < 4; ++ks) {
      bf16x8 bfr = *(const bf16x8*)&vbuf[bi][l & 15][ks * 32 + quad * 8];
      bf16x8 a0 = *(const bf16x8*)(WF + (((t * 8 + 2 * w) * 4 + ks) * 64 + l) * 8);
      bf16x8 a1 = *(const bf16x8*)(WF + (((t * 8 + 2 * w + 1) * 4 + ks) * 64 + l) * 8);
      acc0 = __builtin_amdgcn_mfma_f32_16x16x32_bf16(a0, bfr, acc0, 0, 0, 0);
      acc1 = __builtin_amdgcn_mfma_f32_16x16x32_bf16(a1, bfr, acc1, 0, 0, 0);
    }
  };

  sample(0, 0);
  __syncthreads();
  for (int t = 0; t < 9; ++t) {
    if (t < 8) sample(t + 1, (t + 1) & 1);  // issue gathers early, overlap MFMA
    dotap(t, t & 1);
    __syncthreads();
  }

  // epilogue: BN + SiLU
  const float* BNS = (const float*)(wsb + BNS_B);
  const float* BNB = (const float*)(wsb + BNB_B);
  int pl = p0 + (l & 15);
#pragma unroll
  for (int mi = 0; mi < 2; ++mi) {
    f32x4 acc = mi ? acc1 : acc0;
#pragma unroll
    for (int r = 0; r < 4; ++r) {
      int o = (2 * w + mi) * 16 + quad * 4 + r;
      float v = acc[r] * BNS[o] + BNB[o];
      v = v / (1.f + __expf(-v));
      out[((b * 128 + o) * 64 + ho) * 64 + pl] = v;
    }
  }
}

extern "C" void kernel_launch(void* const* d_in, const int* in_sizes, int n_in,
                              void* d_out, int out_size, void* d_ws, size_t ws_size,
                              hipStream_t stream) {
  const float* x    = (const float*)d_in[0];
  const float* ow   = (const float*)d_in[1];
  const float* ob   = (const float*)d_in[2];
  const float* mw   = (const float*)d_in[3];
  const float* mb   = (const float*)d_in[4];
  const float* wgt  = (const float*)d_in[5];
  const float* gam  = (const float*)d_in[6];
  const float* bet  = (const float*)d_in[7];
  const float* mean = (const float*)d_in[8];
  const float* var  = (const float*)d_in[9];
  char* wsb = (char*)d_ws;
  float* out = (float*)d_out;

  prep_kernel<<<977, 256, 0, stream>>>(x, ow, mw, wgt, gam, bet, mean, var, wsb);
  offmask_kernel<<<512, 256, 0, stream>>>(wsb, ob, mb);
  main_kernel<<<1024, 256, 0, stream>>>(wsb, out);
}